// Round 5
// baseline (680.383 us; speedup 1.0000x reference)
//
#include <hip/hip_runtime.h>
#include <math.h>

typedef unsigned short u16;
typedef unsigned int   u32;

static constexpr int B_=4, C_=256, K_=5, D_=256, N_=4096, IT_=4;
static constexpr float EPS_=1e-5f;

__device__ __forceinline__ float bf2f(u16 u){ u32 x=((u32)u)<<16; float f; __builtin_memcpy(&f,&x,4); return f; }
__device__ __forceinline__ u16 f2bf(float f){ u32 x; __builtin_memcpy(&x,&f,4); u32 r=x+0x7fffu+((x>>16)&1u); return (u16)(r>>16); }
__device__ __forceinline__ float ldin(const void* p, size_t i, int f){
  return f ? ((const float*)p)[i] : bf2f(((const u16*)p)[i]);
}
__device__ __forceinline__ void stout(void* p, size_t i, float v, int f){
  if (f) ((float*)p)[i]=v; else ((u16*)p)[i]=f2bf(v);
}

// ---- 256-thread (4-wave) reductions ----
__device__ __forceinline__ void breduce4(float&a,float&b,float&c,float&d,float* red){
  #pragma unroll
  for(int o=32;o>0;o>>=1){
    a+=__shfl_down(a,o,64); b+=__shfl_down(b,o,64);
    c+=__shfl_down(c,o,64); d+=__shfl_down(d,o,64);
  }
  int w=threadIdx.x>>6;
  __syncthreads();
  if((threadIdx.x&63)==0){ red[w]=a; red[4+w]=b; red[8+w]=c; red[12+w]=d; }
  __syncthreads();
  a=red[0]+red[1]+red[2]+red[3];
  b=red[4]+red[5]+red[6]+red[7];
  c=red[8]+red[9]+red[10]+red[11];
  d=red[12]+red[13]+red[14]+red[15];
}
__device__ __forceinline__ void breduce_minmax(float& mn, float& mx, float* red){
  #pragma unroll
  for(int o=32;o>0;o>>=1){ mn=fminf(mn,__shfl_down(mn,o,64)); mx=fmaxf(mx,__shfl_down(mx,o,64)); }
  int w=threadIdx.x>>6;
  __syncthreads();
  if((threadIdx.x&63)==0){ red[w]=mn; red[4+w]=mx; }
  __syncthreads();
  mn=fminf(fminf(red[0],red[1]),fminf(red[2],red[3]));
  mx=fmaxf(fmaxf(red[4],red[5]),fmaxf(red[6],red[7]));
}
// ---- 1024-thread (16-wave) reduction ----
__device__ __forceinline__ void breduce4_16(float&a,float&b,float&c,float&d,float* red){
  #pragma unroll
  for(int o=32;o>0;o>>=1){
    a+=__shfl_down(a,o,64); b+=__shfl_down(b,o,64);
    c+=__shfl_down(c,o,64); d+=__shfl_down(d,o,64);
  }
  int w=threadIdx.x>>6;
  __syncthreads();
  if((threadIdx.x&63)==0){ red[w]=a; red[16+w]=b; red[32+w]=c; red[48+w]=d; }
  __syncthreads();
  a=0;b=0;c=0;d=0;
  #pragma unroll
  for(int i=0;i<16;++i){ a+=red[i]; b+=red[16+i]; c+=red[32+i]; d+=red[48+i]; }
}

// ---- dtype probe ----
__global__ void probe_kernel(const void* feat, int* flag){
  __shared__ float red[16];
  const u32* p=(const u32*)feat;
  int t=threadIdx.x; int bad=0;
  for(int s=0;s<8;++s){
    u32 wd=p[t+s*256];
    float lo=bf2f((u16)(wd&0xffffu));
    if(!(fabsf(lo)<1e6f)) bad++;
  }
  float bb=(float)bad, z1=0,z2=0,z3=0;
  breduce4(bb,z1,z2,z3,red);
  if(t==0) *flag = (bb>=16.f)?1:0;
}

// ---- prep: weight transposes (-> f32), slot init, ge basis vectors ----
__global__ void prep1_kernel(const int* flag,
    const void* kW, const void* vW, const void* mW, const void* qW, const void* rW,
    const void* Wih, const void* Whh, const void* mu, const void* lsig, const void* noise,
    const void* gW, const void* gb_, const void* mg,
    float* WkT, float* WvT, float* WgT, float* WqT, float* WrT,
    float* WihT, float* WhhT, float* slot, float* gvec)
{
  int f=*flag;
  int e=blockIdx.x*256+threadIdx.x;
  if(e<65536){ int r=e>>8,c=e&255; WkT[c*256+r]=ldin(kW,e,f); return;} e-=65536;
  if(e<65536){ int r=e>>8,c=e&255; WvT[c*256+r]=ldin(vW,e,f); return;} e-=65536;
  if(e<65536){ int r=e>>8,c=e&255; WgT[c*256+r]=ldin(mg,c,f)*ldin(mW,e,f); return;} e-=65536;
  if(e<65536){ int r=e>>8,c=e&255; WqT[c*256+r]=ldin(qW,e,f); return;} e-=65536;
  if(e<65536){ int r=e>>8,c=e&255; WrT[c*256+r]=ldin(rW,e,f); return;} e-=65536;
  if(e<196608){ int r=e>>8,c=e&255; WihT[c*768+r]=ldin(Wih,e,f); return;} e-=196608;
  if(e<196608){ int r=e>>8,c=e&255; WhhT[c*768+r]=ldin(Whh,e,f); return;} e-=196608;
  if(e<5120){ int d=e&255; slot[e]=ldin(mu,d,f)+expf(ldin(lsig,d,f))*ldin(noise,e,f); return;} e-=5120;
  if(e<768){
    int c=e&255, sel=e>>8;
    float v;
    if(sel==0)      v=ldin(gW,c*4+0,f)-ldin(gW,c*4+2,f);
    else if(sel==1) v=ldin(gW,c*4+1,f)-ldin(gW,c*4+3,f);
    else            v=ldin(gb_,c,f);
    gvec[e]=v;
  }
}

// ---- U vectors + quadratic scalars ----
__global__ void uq_kernel(const int* flag, const float* WgT, const void* mW, const void* mb_, const void* mbias,
                          const float* gvec, float* Uvec, float* Qs)
{
  __shared__ float ga[256], gB[256], gc[256]; __shared__ float red[16];
  int t=threadIdx.x; int f=*flag;
  ga[t]=gvec[t]; gB[t]=gvec[256+t]; gc[t]=gvec[512+t];
  __syncthreads();
  float u1=0,u2=0,u3=0,gw=0,bw=0;
  for(int c=0;c<256;++c){
    float wg=WgT[c*256+t];
    u1+=ga[c]*wg; u2+=gB[c]*wg; u3+=gc[c]*wg; gw+=wg;
    bw+=ldin(mb_,c,f)*ldin(mW,(size_t)t*256+c,f);
  }
  Uvec[t]=u1; Uvec[256+t]=u2; Uvec[512+t]=u3; Uvec[768+t]=gw;
  Uvec[1024+t]=bw+ldin(mbias,t,f);
  float a=ga[t], b=gB[t], cc=gc[t];
  float s0=a*a,s1=b*b,s2=cc*cc,s3=a*b; breduce4(s0,s1,s2,s3,red);
  float s4=a*cc,s5=b*cc,s6=a,s7=b;     breduce4(s4,s5,s6,s7,red);
  float s8=cc,z1=0,z2=0,z3=0;          breduce4(s8,z1,z2,z3,red);
  if(t==0){
    Qs[0]=s0; Qs[1]=s1; Qs[2]=s2; Qs[3]=s3; Qs[4]=s4; Qs[5]=s5;
    Qs[6]=s6*(1.f/256.f); Qs[7]=s7*(1.f/256.f); Qs[8]=s8*(1.f/256.f);
  }
}

// ---- fg_pos ----
__global__ void fgpos_kernel(const int* flag, const void* mask, float* fg, void* out)
{
  __shared__ float red[16];
  int k=blockIdx.x, t=threadIdx.x, f=*flag;
  float sx=0,sy=0,sm=0;
  for(int s=0;s<16;++s){
    int p=t+s*256;
    float m=ldin(mask,(size_t)k*N_+p,f);
    int i=p>>6, j=p&63;
    float x=(2*j+1)*(1.0f/64.0f)-1.0f;
    float y=(2*i+1)*(1.0f/64.0f)-1.0f;
    sx+=x*m; sy+=y*m; sm+=m;
  }
  float d=0;
  breduce4(sx,sy,sm,d,red);
  if(t==0){
    float inv=1.0f/(sm+1e-5f);
    float fx=sx*inv, fy=sy*inv;
    fg[k*2]=fx; fg[k*2+1]=fy;
    for(int b=0;b<B_;++b){
      stout(out, 5120+(b*K_+k)*2+0, fx, f);
      stout(out, 5120+(b*K_+k)*2+1, fy, f);
    }
  }
}

// ---- base: LN(feat) -> kb/vb -> scalars + PkT (transposed) / Pv GEMMs. Zero __syncthreads. ----
__global__ void __launch_bounds__(256) base_kernel(const int* flag, const void* feat, const void* ng, const void* nb,
    const float* WkT, const float* WvT, const float* WgT, const float* gvec,
    float* scal, float* PkT, float* Pv)
{
  __shared__ float A[16][256];
  __shared__ float Vb[16][256];
  int t=threadIdx.x, f=*flag;
  int w=t>>6, l=t&63, d0=l*4;
  int row0=blockIdx.x*16;
  // wave-local LN: wave w owns rows 4w..4w+3
  float g0=ldin(ng,l,f), g1=ldin(ng,l+64,f), g2=ldin(ng,l+128,f), g3=ldin(ng,l+192,f);
  float b0=ldin(nb,l,f), b1=ldin(nb,l+64,f), b2=ldin(nb,l+128,f), b3=ldin(nb,l+192,f);
  #pragma unroll
  for(int r4=0;r4<4;++r4){
    int r=4*w+r4; size_t base=(size_t)(row0+r)*256;
    float x0=ldin(feat,base+l,f), x1=ldin(feat,base+l+64,f),
          x2=ldin(feat,base+l+128,f), x3=ldin(feat,base+l+192,f);
    float s=x0+x1+x2+x3, s2=x0*x0+x1*x1+x2*x2+x3*x3;
    #pragma unroll
    for(int o=32;o>0;o>>=1){ s+=__shfl_xor(s,o,64); s2+=__shfl_xor(s2,o,64); }
    float m=s*(1.f/256.f), inv=rsqrtf(s2*(1.f/256.f)-m*m+EPS_);
    A[r][l]    =(x0-m)*inv*g0+b0;
    A[r][l+64] =(x1-m)*inv*g1+b1;
    A[r][l+128]=(x2-m)*inv*g2+b2;
    A[r][l+192]=(x3-m)*inv*g3+b3;
  }
  // pass1: kb/vb = fn @ Wk/Wv (wave reads only its own rows)
  float ak[4][4]={{0}}, av[4][4]={{0}};
  for(int c0=0;c0<256;c0+=4){
    float4 a4[4];
    #pragma unroll
    for(int r=0;r<4;++r) a4[r]=*(float4*)&A[4*w+r][c0];
    #pragma unroll
    for(int j=0;j<4;++j){
      float4 wk=*(const float4*)(WkT+(size_t)(c0+j)*256+d0);
      float4 wv=*(const float4*)(WvT+(size_t)(c0+j)*256+d0);
      #pragma unroll
      for(int r=0;r<4;++r){
        float fa=((const float*)&a4[r])[j];
        ak[r][0]+=fa*wk.x; ak[r][1]+=fa*wk.y; ak[r][2]+=fa*wk.z; ak[r][3]+=fa*wk.w;
        av[r][0]+=fa*wv.x; av[r][1]+=fa*wv.y; av[r][2]+=fa*wv.z; av[r][3]+=fa*wv.w;
      }
    }
  }
  #pragma unroll
  for(int r=0;r<4;++r){
    *(float4*)&A[4*w+r][d0] =make_float4(ak[r][0],ak[r][1],ak[r][2],ak[r][3]);
    *(float4*)&Vb[4*w+r][d0]=make_float4(av[r][0],av[r][1],av[r][2],av[r][3]);
  }
  // per-row scalars (wave-local)
  float gA0=gvec[l], gA1=gvec[l+64], gA2=gvec[l+128], gA3=gvec[l+192];
  float gB0=gvec[256+l], gB1=gvec[256+l+64], gB2=gvec[256+l+128], gB3=gvec[256+l+192];
  float gC0=gvec[512+l], gC1=gvec[512+l+64], gC2=gvec[512+l+128], gC3=gvec[512+l+192];
  for(int r4=0;r4<4;++r4){
    int r=4*w+r4;
    float k0=A[r][l], k1=A[r][l+64], k2=A[r][l+128], k3=A[r][l+192];
    float x0=Vb[r][l], x1=Vb[r][l+64], x2=Vb[r][l+128], x3=Vb[r][l+192];
    float v0=k0+k1+k2+k3;
    float v1=k0*k0+k1*k1+k2*k2+k3*k3;
    float v2=k0*gA0+k1*gA1+k2*gA2+k3*gA3;
    float v3=k0*gB0+k1*gB1+k2*gB2+k3*gB3;
    float v4=k0*gC0+k1*gC1+k2*gC2+k3*gC3;
    float v5=x0+x1+x2+x3;
    float v6=x0*x0+x1*x1+x2*x2+x3*x3;
    float v7=x0*gA0+x1*gA1+x2*gA2+x3*gA3;
    float v8=x0*gB0+x1*gB1+x2*gB2+x3*gB3;
    float v9=x0*gC0+x1*gC1+x2*gC2+x3*gC3;
    #pragma unroll
    for(int o=32;o>0;o>>=1){
      v0+=__shfl_down(v0,o,64); v1+=__shfl_down(v1,o,64); v2+=__shfl_down(v2,o,64);
      v3+=__shfl_down(v3,o,64); v4+=__shfl_down(v4,o,64); v5+=__shfl_down(v5,o,64);
      v6+=__shfl_down(v6,o,64); v7+=__shfl_down(v7,o,64); v8+=__shfl_down(v8,o,64);
      v9+=__shfl_down(v9,o,64);
    }
    if(l==0){
      float* sc=scal+(size_t)(row0+r)*10;
      sc[0]=v0; sc[1]=v1; sc[2]=v2; sc[3]=v3; sc[4]=v4;
      sc[5]=v5; sc[6]=v6; sc[7]=v7; sc[8]=v8; sc[9]=v9;
    }
  }
  // pass2: Pk/Pv = kb/vb @ WgT
  float pk[4][4]={{0}}, pv[4][4]={{0}};
  for(int c0=0;c0<256;c0+=4){
    float4 a4[4], v4_[4];
    #pragma unroll
    for(int r=0;r<4;++r){ a4[r]=*(float4*)&A[4*w+r][c0]; v4_[r]=*(float4*)&Vb[4*w+r][c0]; }
    #pragma unroll
    for(int j=0;j<4;++j){
      float4 wg=*(const float4*)(WgT+(size_t)(c0+j)*256+d0);
      #pragma unroll
      for(int r=0;r<4;++r){
        float fa=((const float*)&a4[r])[j], fb=((const float*)&v4_[r])[j];
        pk[r][0]+=fa*wg.x; pk[r][1]+=fa*wg.y; pk[r][2]+=fa*wg.z; pk[r][3]+=fa*wg.w;
        pv[r][0]+=fb*wg.x; pv[r][1]+=fb*wg.y; pv[r][2]+=fb*wg.z; pv[r][3]+=fb*wg.w;
      }
    }
  }
  #pragma unroll
  for(int r=0;r<4;++r){
    int row=row0+4*w+r;
    #pragma unroll
    for(int j=0;j<4;++j) PkT[(size_t)(d0+j)*16384 + row] = pk[r][j];
    *(float4*)(Pv+(size_t)row*256+d0)=make_float4(pv[r][0],pv[r][1],pv[r][2],pv[r][3]);
  }
}

// ---- q projection (iter 0 only) ----
__global__ void q_kernel(const int* flag, const float* slot, const void* qg, const void* qb_,
                         const float* WqT, const float* Uvec, float* qbuf, float* qsc)
{
  __shared__ float Lq[256]; __shared__ float qsh[256]; __shared__ float red[16];
  int bk=blockIdx.x, t=threadIdx.x, f=*flag;
  float x=slot[bk*256+t];
  float s=x,s2=x*x,z0=0,z1=0; breduce4(s,s2,z0,z1,red);
  float m=s*(1.f/256.f), v=s2*(1.f/256.f)-m*m;
  Lq[t]=(x-m)*rsqrtf(v+EPS_)*ldin(qg,t,f)+ldin(qb_,t,f);
  __syncthreads();
  float acc=0;
  for(int c=0;c<256;++c) acc+=Lq[c]*WqT[c*256+t];
  qbuf[bk*256+t]=acc; qsh[t]=acc;
  __syncthreads();
  float q=qsh[t];
  float s0=q*Uvec[t], s1=q*Uvec[256+t], s2b=q*Uvec[512+t], s3=q*Uvec[768+t];
  breduce4(s0,s1,s2b,s3,red);
  float s4=q*Uvec[1024+t], z2=0,z3=0,z4=0;
  breduce4(s4,z2,z3,z4,red);
  if(t==0){ qsc[bk*8+0]=s0; qsc[bk*8+1]=s1; qsc[bk*8+2]=s2b; qsc[bk*8+3]=s3; qsc[bk*8+4]=s4; }
}

// ---- logits: lane-per-n coalesced PkT reads, all 5 k per lane, partial softmax per 256-chunk ----
__global__ void __launch_bounds__(256) logits_kernel(const int* flag, const float* qbuf, const float* PkT,
    const float* scal, const float* Qs, const float* qsc, const float* fg, const void* mask,
    float* logits, float* pmax, float* psum)
{
  __shared__ float q5[5][256];
  __shared__ float qs5[5][8];
  __shared__ float fgs[10];
  __shared__ float Qss[9];
  __shared__ float wred[4][5][2];
  int t=threadIdx.x, f=*flag;
  int b=blockIdx.x>>4, chunk=blockIdx.x&15;
  int w=t>>6, l=t&63;
  int n=chunk*256 + w*64 + l;
  #pragma unroll
  for(int k=0;k<5;++k) q5[k][t]=qbuf[(size_t)(b*5+k)*256+t];
  if(t<40) qs5[t>>3][t&7]=qsc[(size_t)(b*5+(t>>3))*8+(t&7)];
  if(t<10) fgs[t]=fg[t];
  if(t<9)  Qss[t]=Qs[t];
  __syncthreads();
  size_t row=(size_t)b*N_+n;
  float dk0=0,dk1=0,dk2=0,dk3=0,dk4=0;
  for(int c0=0;c0<256;c0+=4){
    float4 qv0=*(float4*)&q5[0][c0], qv1=*(float4*)&q5[1][c0], qv2=*(float4*)&q5[2][c0];
    float4 qv3=*(float4*)&q5[3][c0], qv4=*(float4*)&q5[4][c0];
    #pragma unroll
    for(int j=0;j<4;++j){
      float pvv=PkT[(size_t)(c0+j)*16384 + row];
      dk0+=pvv*((const float*)&qv0)[j]; dk1+=pvv*((const float*)&qv1)[j];
      dk2+=pvv*((const float*)&qv2)[j]; dk3+=pvv*((const float*)&qv3)[j];
      dk4+=pvv*((const float*)&qv4)[j];
    }
  }
  float dk[5]={dk0,dk1,dk2,dk3,dk4};
  const float* sc=scal+row*10;
  float s0=sc[0], s1=sc[1], s2=sc[2], s3=sc[3], s4=sc[4];
  float wmv[5], wsv[5];
  int jx=n&63, iy=n>>6;
  #pragma unroll
  for(int k=0;k<5;++k){
    float rx=(2*jx+1)*(1.f/64.f)-1.f-fgs[2*k];
    float ry=(2*iy+1)*(1.f/64.f)-1.f-fgs[2*k+1];
    float qge=rx*rx*Qss[0]+ry*ry*Qss[1]+Qss[2]+2.f*(rx*ry*Qss[3]+rx*Qss[4]+ry*Qss[5]);
    float mk=s0*(1.f/256.f)+rx*Qss[6]+ry*Qss[7]+Qss[8];
    float sxk=s1+2.f*(rx*s2+ry*s3+s4)+qge;
    float invK=rsqrtf(sxk*(1.f/256.f)-mk*mk+EPS_);
    float lg=invK*(dk[k]+rx*qs5[k][0]+ry*qs5[k][1]+qs5[k][2]-mk*qs5[k][3])+qs5[k][4];
    float mval=ldin(mask,(size_t)k*N_+n,f);
    lg = (mval==0.f)? -1e9f : lg*0.0625f;
    logits[((size_t)(b*5+k))*N_+n]=lg;
    // wave partial softmax
    float wm=lg;
    #pragma unroll
    for(int o=32;o>0;o>>=1) wm=fmaxf(wm,__shfl_xor(wm,o,64));
    float ex=expf(lg-wm);
    #pragma unroll
    for(int o=32;o>0;o>>=1) ex+=__shfl_xor(ex,o,64);
    wmv[k]=wm; wsv[k]=ex;
  }
  if(l==0){
    #pragma unroll
    for(int k=0;k<5;++k){ wred[w][k][0]=wmv[k]; wred[w][k][1]=wsv[k]; }
  }
  __syncthreads();
  if(t<5){
    float M=fmaxf(fmaxf(wred[0][t][0],wred[1][t][0]),fmaxf(wred[2][t][0],wred[3][t][0]));
    float S=wred[0][t][1]*expf(wred[0][t][0]-M)+wred[1][t][1]*expf(wred[1][t][0]-M)
           +wred[2][t][1]*expf(wred[2][t][0]-M)+wred[3][t][1]*expf(wred[3][t][0]-M);
    pmax[(size_t)(b*16+chunk)*5+t]=M;
    psum[(size_t)(b*16+chunk)*5+t]=S;
  }
}

// ---- upd: softmax-combine inline, w=attn*invV on the fly, Pv dots + ssc partials ----
__global__ void __launch_bounds__(256) upd_kernel(const float* logits, const float* pmax, const float* psum,
    const float* scal, const float* Qs, const float* fg, const float* Pv,
    float* updpart, float* sscp)
{
  __shared__ float MS[5][2];
  __shared__ float pm_[80], ps_[80];
  __shared__ float part[4][5][256];
  __shared__ float sred[4][5][4];
  int t=threadIdx.x, w=t>>6, l=t&63;
  int b=blockIdx.x>>6, ch=blockIdx.x&63;
  int n0=ch*64;
  if(t<80){ int kk=t/16, cc=t&15;
    pm_[t]=pmax[(size_t)(b*16+cc)*5+kk]; ps_[t]=psum[(size_t)(b*16+cc)*5+kk]; }
  __syncthreads();
  if(t<5){
    float M=-1e30f;
    for(int c=0;c<16;++c) M=fmaxf(M,pm_[t*16+c]);
    float S=0;
    for(int c=0;c<16;++c) S+=ps_[t*16+c]*expf(pm_[t*16+c]-M);
    MS[t][0]=M; MS[t][1]=1.0f/S;
  }
  __syncthreads();
  float QA=Qs[0],QB=Qs[1],QC=Qs[2],QAB=Qs[3],QAC=Qs[4],QBC=Qs[5],mA=Qs[6],mB=Qs[7],mC=Qs[8];
  float fgl[10];
  #pragma unroll
  for(int i=0;i<10;++i) fgl[i]=fg[i];
  float acc[5][4]={{0}};
  float swx[5]={0,0,0,0,0}, swy[5]={0,0,0,0,0}, sw[5]={0,0,0,0,0}, swm[5]={0,0,0,0,0};
  for(int rr=0;rr<16;++rr){
    int n=n0+w*16+rr;
    size_t row=(size_t)b*N_+n;
    float4 p=*(const float4*)(Pv+row*256+l*4);
    const float* sc=scal+row*10;
    float s5=sc[5], s6=sc[6], s7=sc[7], s8=sc[8], s9=sc[9];
    int jx=n&63, iy=n>>6;
    #pragma unroll
    for(int k=0;k<5;++k){
      float lg=logits[((size_t)(b*5+k))*N_+n];
      float rx=(2*jx+1)*(1.f/64.f)-1.f-fgl[2*k];
      float ry=(2*iy+1)*(1.f/64.f)-1.f-fgl[2*k+1];
      float qge=rx*rx*QA+ry*ry*QB+QC+2.f*(rx*ry*QAB+rx*QAC+ry*QBC);
      float mv=s5*(1.f/256.f)+rx*mA+ry*mB+mC;
      float sxv=s6+2.f*(rx*s7+ry*s8+s9)+qge;
      float iv=rsqrtf(sxv*(1.f/256.f)-mv*mv+EPS_);
      float wgt=expf(lg-MS[k][0])*MS[k][1]*iv;
      acc[k][0]+=wgt*p.x; acc[k][1]+=wgt*p.y; acc[k][2]+=wgt*p.z; acc[k][3]+=wgt*p.w;
      sw[k]+=wgt; swx[k]+=wgt*rx; swy[k]+=wgt*ry; swm[k]+=wgt*mv;
    }
  }
  #pragma unroll
  for(int k=0;k<5;++k)
    *(float4*)&part[w][k][l*4]=make_float4(acc[k][0],acc[k][1],acc[k][2],acc[k][3]);
  if(l==0){
    #pragma unroll
    for(int k=0;k<5;++k){ sred[w][k][0]=swx[k]; sred[w][k][1]=swy[k]; sred[w][k][2]=sw[k]; sred[w][k][3]=swm[k]; }
  }
  __syncthreads();
  #pragma unroll
  for(int k=0;k<5;++k){
    float v=part[0][k][t]+part[1][k][t]+part[2][k][t]+part[3][k][t];
    updpart[((size_t)blockIdx.x*5+k)*256+t]=v;
  }
  if(t<20){
    int kk=t>>2, j=t&3;
    sscp[((size_t)blockIdx.x*5+kk)*4+j]=sred[0][kk][j]+sred[1][kk][j]+sred[2][kk][j]+sred[3][kk][j];
  }
}

// ---- GRU + res MLP + slot out + next-iter q projection; 1024 threads, 4-way c-split ----
__global__ void __launch_bounds__(1024) gru_kernel(const int* flag, float* slot, const float* updpart,
    const float* sscp, const float* Uvec,
    const float* WihT, const float* WhhT, const void* bih, const void* bhh,
    const void* rg, const void* rb_, const float* WrT, const void* rbias,
    const void* qg, const void* qb_, const float* WqT, float* qbuf, float* qsc, void* out)
{
  __shared__ float u[256], h[256], sn[256];
  __shared__ float part[4][6][256];
  __shared__ float red[64];
  __shared__ float cvec[4];
  int tid=threadIdx.x, t=tid&255, g=tid>>8;
  int bk=blockIdx.x, k=bk%K_, b=bk/K_;
  int f=*flag;
  // phase A: reduce upd partials
  float ua=0;
  for(int ch=g*16; ch<g*16+16; ++ch) ua += updpart[(((size_t)(b*64+ch))*5+k)*256+t];
  part[g][0][t]=ua;
  if(t<4){
    float s=0;
    for(int ch=g*16; ch<g*16+16; ++ch) s += sscp[(((size_t)(b*64+ch))*5+k)*4+t];
    part[g][1][t]=s;
  }
  __syncthreads();
  if(g==0 && t<4) cvec[t]=part[0][1][t]+part[1][1][t]+part[2][1][t]+part[3][1][t];
  __syncthreads();
  if(g==0){
    float uu=part[0][0][t]+part[1][0][t]+part[2][0][t]+part[3][0][t];
    u[t]=uu+cvec[0]*Uvec[t]+cvec[1]*Uvec[256+t]+cvec[2]*Uvec[512+t]-cvec[3]*Uvec[768+t]+Uvec[1024+t];
    h[t]=slot[bk*256+t];
  }
  __syncthreads();
  // phase B: GRU matvec, group g covers c in [64g, 64g+64)
  float p0=0,p1=0,p2=0,p3=0,p4=0,p5=0;
  int c0=g*64;
  for(int cc=0;cc<64;++cc){
    int c=c0+cc;
    float uc=u[c], hc=h[c];
    const float* wi=WihT+(size_t)c*768+t;
    const float* wh=WhhT+(size_t)c*768+t;
    p0+=uc*wi[0]; p1+=uc*wi[256]; p2+=uc*wi[512];
    p3+=hc*wh[0]; p4+=hc*wh[256]; p5+=hc*wh[512];
  }
  part[g][0][t]=p0; part[g][1][t]=p1; part[g][2][t]=p2;
  part[g][3][t]=p3; part[g][4][t]=p4; part[g][5][t]=p5;
  __syncthreads();
  float hn=0;
  if(g==0){
    float gi0=ldin(bih,t,f)+part[0][0][t]+part[1][0][t]+part[2][0][t]+part[3][0][t];
    float gi1=ldin(bih,256+t,f)+part[0][1][t]+part[1][1][t]+part[2][1][t]+part[3][1][t];
    float gi2=ldin(bih,512+t,f)+part[0][2][t]+part[1][2][t]+part[2][2][t]+part[3][2][t];
    float gh0=ldin(bhh,t,f)+part[0][3][t]+part[1][3][t]+part[2][3][t]+part[3][3][t];
    float gh1=ldin(bhh,256+t,f)+part[0][4][t]+part[1][4][t]+part[2][4][t]+part[3][4][t];
    float gh2=ldin(bhh,512+t,f)+part[0][5][t]+part[1][5][t]+part[2][5][t]+part[3][5][t];
    float r=1.f/(1.f+expf(-(gi0+gh0)));
    float z=1.f/(1.f+expf(-(gi1+gh1)));
    float nn=tanhf(gi2+r*gh2);
    hn=(1.f-z)*nn+z*h[t];
  }
  // LN(hn)
  float s=hn, sq=hn*hn, za=0, zb=0;
  breduce4_16(s,sq,za,zb,red);
  if(g==0){
    float m=s*(1.f/256.f), var=sq*(1.f/256.f)-m*m;
    u[t]=(hn-m)*rsqrtf(var+EPS_)*ldin(rg,t,f)+ldin(rb_,t,f);   // u := Ln
  }
  __syncthreads();
  // phase C: res matvec
  float pr=0;
  for(int cc=0;cc<64;++cc){ int c=c0+cc; pr+=u[c]*WrT[(size_t)c*256+t]; }
  part[g][0][t]=pr;
  __syncthreads();
  if(g==0){
    float acc=ldin(rbias,t,f)+h[t]+part[0][0][t]+part[1][0][t]+part[2][0][t]+part[3][0][t];
    slot[bk*256+t]=acc;
    stout(out, (size_t)bk*256+t, acc, f);
    sn[t]=acc;
  }
  __syncthreads();
  // phase D: next-iter q projection
  float xs=(g==0)? sn[t]:0.f;
  float xq=xs*xs, zc=0, zd=0;
  breduce4_16(xs,xq,zc,zd,red);
  if(g==0){
    float m=xs*(1.f/256.f), var=xq*(1.f/256.f)-m*m;
    u[t]=(sn[t]-m)*rsqrtf(var+EPS_)*ldin(qg,t,f)+ldin(qb_,t,f);  // u := Lq
  }
  __syncthreads();
  float pq=0;
  for(int cc=0;cc<64;++cc){ int c=c0+cc; pq+=u[c]*WqT[(size_t)c*256+t]; }
  part[g][0][t]=pq;
  __syncthreads();
  float qv=0.f;
  if(g==0){
    qv=part[0][0][t]+part[1][0][t]+part[2][0][t]+part[3][0][t];
    qbuf[bk*256+t]=qv;
  }
  float a0=(g==0)? qv*Uvec[t]:0.f;
  float a1=(g==0)? qv*Uvec[256+t]:0.f;
  float a2=(g==0)? qv*Uvec[512+t]:0.f;
  float a3=(g==0)? qv*Uvec[768+t]:0.f;
  breduce4_16(a0,a1,a2,a3,red);
  float a4=(g==0)? qv*Uvec[1024+t]:0.f;
  float z1=0,z2=0,z3=0;
  breduce4_16(a4,z1,z2,z3,red);
  if(tid==0){ qsc[bk*8+0]=a0; qsc[bk*8+1]=a1; qsc[bk*8+2]=a2; qsc[bk*8+3]=a3; qsc[bk*8+4]=a4; }
}

// ---- attn_vis from last-iter logits ----
__global__ void vis_kernel(const int* flag, const float* logits, const float* pmax, const float* psum, void* out)
{
  __shared__ float red[16];
  __shared__ float MSv[2];
  int bk=blockIdx.x, t=threadIdx.x, f=*flag;
  int k=bk%K_, b=bk/K_;
  if(t==0){
    float M=-1e30f;
    for(int c=0;c<16;++c) M=fmaxf(M,pmax[(size_t)(b*16+c)*5+k]);
    float S=0;
    for(int c=0;c<16;++c) S+=psum[(size_t)(b*16+c)*5+k]*expf(pmax[(size_t)(b*16+c)*5+k]-M);
    MSv[0]=M; MSv[1]=1.0f/S;
  }
  __syncthreads();
  float M=MSv[0], Sinv=MSv[1];
  float a[16]; float mn=1e30f, mx=-1e30f;
  for(int s=0;s<16;++s){
    a[s]=expf(logits[(size_t)bk*N_+t+s*256]-M)*Sinv;
    mn=fminf(mn,a[s]); mx=fmaxf(mx,a[s]);
  }
  breduce_minmax(mn,mx,red);
  float inv=1.0f/(mx-mn+1e-5f);
  for(int s=0;s<16;++s) stout(out, 5160+(size_t)bk*N_+t+s*256, (a[s]-mn)*inv, f);
}

extern "C" void kernel_launch(void* const* d_in, const int* in_sizes, int n_in,
                              void* d_out, int out_size, void* d_ws, size_t ws_size,
                              hipStream_t stream)
{
  const void* feat =d_in[0];  const void* mask =d_in[1];  const void* noise=d_in[2];
  const void* mu   =d_in[3];  const void* lsig =d_in[4];  const void* ng   =d_in[5];
  const void* nb   =d_in[6];  const void* gW   =d_in[7];  const void* gb_  =d_in[8];
  const void* kW   =d_in[9];  const void* vW   =d_in[10]; const void* mg   =d_in[11];
  const void* mb_  =d_in[12]; const void* mW   =d_in[13]; const void* mbias=d_in[14];
  const void* qg   =d_in[15]; const void* qb_  =d_in[16]; const void* qW   =d_in[17];
  const void* Wih  =d_in[18]; const void* Whh  =d_in[19]; const void* bih  =d_in[20];
  const void* bhh  =d_in[21]; const void* rg   =d_in[22]; const void* rb_  =d_in[23];
  const void* rW   =d_in[24]; const void* rbias=d_in[25];

  char* p=(char*)d_ws;
  auto alloc=[&](size_t bytes)->char*{ char* r=p; p+=(bytes+255)&~(size_t)255; return r; };
  int*   flag   =(int*)  alloc(256);
  float* fg     =(float*)alloc(64);
  float* slot   =(float*)alloc(5120*4);
  float* qbuf   =(float*)alloc(5120*4);
  float* qsc    =(float*)alloc(160*4);
  float* logits =(float*)alloc((size_t)81920*4);
  float* pmax   =(float*)alloc(320*4);
  float* psum   =(float*)alloc(320*4);
  float* updpart=(float*)alloc((size_t)256*5*256*4);
  float* sscp   =(float*)alloc((size_t)256*5*4*4);
  float* WkT    =(float*)alloc((size_t)65536*4);
  float* WvT    =(float*)alloc((size_t)65536*4);
  float* WgT    =(float*)alloc((size_t)65536*4);
  float* WqT    =(float*)alloc((size_t)65536*4);
  float* WrT    =(float*)alloc((size_t)65536*4);
  float* WihT   =(float*)alloc((size_t)196608*4);
  float* WhhT   =(float*)alloc((size_t)196608*4);
  float* gvec   =(float*)alloc(768*4);
  float* Uvec   =(float*)alloc(1280*4);
  float* Qs     =(float*)alloc(64);
  float* scal   =(float*)alloc((size_t)163840*4);
  float* PkT    =(float*)alloc((size_t)16384*256*4);
  float* Pv     =(float*)alloc((size_t)16384*256*4);

  probe_kernel<<<1,256,0,stream>>>(feat, flag);
  prep1_kernel<<<2839,256,0,stream>>>(flag,kW,vW,mW,qW,rW,Wih,Whh,mu,lsig,noise,gW,gb_,mg,
                                      WkT,WvT,WgT,WqT,WrT,WihT,WhhT,slot,gvec);
  uq_kernel<<<1,256,0,stream>>>(flag,WgT,mW,mb_,mbias,gvec,Uvec,Qs);
  fgpos_kernel<<<K_,256,0,stream>>>(flag,mask,fg,d_out);
  base_kernel<<<(B_*N_)/16,256,0,stream>>>(flag,feat,ng,nb,WkT,WvT,WgT,gvec,scal,PkT,Pv);
  q_kernel<<<B_*K_,256,0,stream>>>(flag,slot,qg,qb_,WqT,Uvec,qbuf,qsc);
  for(int it=0; it<IT_; ++it){
    logits_kernel<<<B_*16,256,0,stream>>>(flag,qbuf,PkT,scal,Qs,qsc,fg,mask,logits,pmax,psum);
    upd_kernel<<<B_*64,256,0,stream>>>(logits,pmax,psum,scal,Qs,fg,Pv,updpart,sscp);
    gru_kernel<<<B_*K_,1024,0,stream>>>(flag,slot,updpart,sscp,Uvec,WihT,WhhT,bih,bhh,
                                        rg,rb_,WrT,rbias,qg,qb_,WqT,qbuf,qsc,d_out);
  }
  vis_kernel<<<B_*K_,256,0,stream>>>(flag,logits,pmax,psum,d_out);
}